// Round 6
// baseline (542.838 us; speedup 1.0000x reference)
//
#include <hip/hip_runtime.h>
#include <math.h>

// Problem constants (from reference)
#define NB   4
#define NC   4
#define NF   257
#define NFRM 2000
#define PLANE (NB*NC*NF*NFRM)   // 8,224,000
#define EPS  1e-3f
#define INV_FN (1.0f/514000.0f) // 1/(NF*NFRM)

#define RFC  29                 // k_r frequency chunks
#define RFP  9                  // f per chunk (29*9=261 >= 257)
#define UT   512                // k_u threads
#define UK   4                  // contiguous frames per thread (500*4 = 2000)

__device__ __forceinline__ float2 cmulf(float2 a, float2 b) {
  return make_float2(a.x*b.x - a.y*b.y, a.x*b.y + a.y*b.x);
}

// DPP wave-64 sum: after this, lane 63 of each wave holds the full wave sum.
#define DPP_STAGE(x, CTRL)                                                \
  x += __int_as_float(__builtin_amdgcn_update_dpp(                        \
        0, __float_as_int(x), CTRL, 0xf, 0xf, true))

template<int N>
__device__ __forceinline__ void wave_reduceN(float* acc) {
  #pragma unroll
  for (int i=0;i<N;i++) {
    float xv = acc[i];
    DPP_STAGE(xv, 0x111);   // row_shr:1
    DPP_STAGE(xv, 0x112);   // row_shr:2
    DPP_STAGE(xv, 0x114);   // row_shr:4
    DPP_STAGE(xv, 0x118);   // row_shr:8
    DPP_STAGE(xv, 0x142);   // row_bcast:15
    DPP_STAGE(xv, 0x143);   // row_bcast:31
    acc[i] = xv;            // lane 63: wave total
  }
}

// zero rsum (32000) + gpart (48)
__global__ __launch_bounds__(256)
void k_zero(float* __restrict__ rsum, float* __restrict__ gpart) {
  int idx = blockIdx.x*256 + threadIdx.x;
  if (idx < 32000) rsum[idx] = 0.f;
  else if (idx < 32048) gpart[idx-32000] = 0.f;
}

// r-pass: rsum[b,c,n] += sum over f-chunk of |X|^2 (atomic), gpart[bc] += total
__global__ __launch_bounds__(256)
void k_r(const float* __restrict__ Xr, const float* __restrict__ Xi,
         float* __restrict__ rsum, float* __restrict__ gpart)
{
  const int tid = threadIdx.x;
  const int q   = blockIdx.x*256 + tid;   // float4 index over n, 500 valid
  const int fc  = blockIdx.y;
  const int bc  = blockIdx.z;
  float4 s4 = make_float4(0.f,0.f,0.f,0.f);
  if (q < 500) {
    const int f0 = fc*RFP;
    const int f1 = (f0+RFP < NF) ? (f0+RFP) : NF;
    const float4* r4 = (const float4*)(Xr + (size_t)(bc*NF+f0)*NFRM) + q;
    const float4* i4 = (const float4*)(Xi + (size_t)(bc*NF+f0)*NFRM) + q;
    for (int f=f0; f<f1; ++f) {
      float4 a = *r4, b2 = *i4;
      s4.x += a.x*a.x + b2.x*b2.x;
      s4.y += a.y*a.y + b2.y*b2.y;
      s4.z += a.z*a.z + b2.z*b2.z;
      s4.w += a.w*a.w + b2.w*b2.w;
      r4 += 500; i4 += 500;
    }
    float* rp = rsum + bc*NFRM + q*4;
    atomicAdd(rp+0, s4.x); atomicAdd(rp+1, s4.y);
    atomicAdd(rp+2, s4.z); atomicAdd(rp+3, s4.w);
  }
  float t = s4.x+s4.y+s4.z+s4.w;
  #pragma unroll
  for (int o=32;o;o>>=1) t += __shfl_down(t, o);
  __shared__ float wred[4];
  if ((tid & 63) == 0) wred[tid>>6] = t;
  __syncthreads();
  if (tid == 0) atomicAdd(&gpart[bc], wred[0]+wred[1]+wred[2]+wred[3]);
}

// weights kernel: w0g[b,c,n] = g[b,c] / max(2*sqrt(rsum), 1e-5); re-zero rsum
__global__ __launch_bounds__(256)
void k_w(float* __restrict__ rsum, const float* __restrict__ gpart,
         float* __restrict__ w0g)
{
  int idx = blockIdx.x*256 + threadIdx.x;   // 125*256 = 32000 exact
  int bc  = idx / NFRM;
  float g = fmaxf(gpart[bc]*INV_FN, EPS);
  float r = rsum[idx];
  float s = fmaxf(2.0f*sqrtf(r), 1e-5f);
  w0g[idx] = g * __builtin_amdgcn_rcpf(s);
  rsum[idx] = 0.f;
}

// Block reduce of 32 values: DPP wave-reduce, lane-63 b128 writes, 32-thread
// cross-wave sum, broadcast b128 re-read. 2 barriers.
#define REDUCE32()                                                        \
  {                                                                       \
    wave_reduceN<32>(acc);                                                \
    if ((tid & 63) == 63) {                                               \
      const int wid = tid >> 6;                                           \
      _Pragma("unroll")                                                   \
      for (int j=0;j<8;j++)                                               \
        *(float4*)&wpart[wid][j*4] =                                      \
          make_float4(acc[j*4],acc[j*4+1],acc[j*4+2],acc[j*4+3]);         \
    }                                                                     \
    __syncthreads();                                                      \
    if (tid < 32) {                                                       \
      float t = 0.f;                                                      \
      _Pragma("unroll")                                                   \
      for (int w=0;w<8;w++) t += wpart[w][tid];                           \
      vredL[tid] = t;                                                     \
    }                                                                     \
    __syncthreads();                                                      \
    _Pragma("unroll")                                                     \
    for (int j=0;j<8;j++) {                                               \
      float4 vv = *(const float4*)&vredL[j*4];                            \
      vsum[j*4]=vv.x; vsum[j*4+1]=vv.y; vsum[j*4+2]=vv.z; vsum[j*4+3]=vv.w; \
    }                                                                     \
  }

// Per-(b,f) update kernel. 512 threads, 4 CONTIGUOUS frames each, 2 blocks/CU.
// Sweeps fused in PAIRS via rank-1 cross-correction: 6 block reductions total.
template<bool FIRST, bool LAST>
__global__ __launch_bounds__(UT, 2)
void k_u(const float* Xsr, const float* Xsi,                 // current X source
         const float* __restrict__ Xor_, const float* __restrict__ Xoi_, // original (taps)
         float* Xdr, float* Xdi,                             // dest (may alias src)
         const float* __restrict__ w0gbuf,
         const float* __restrict__ gpart,
         float2* __restrict__ Wg)
{
  __shared__ __align__(16) float wpart[8][32];
  __shared__ __align__(16) float vredL[32];
  __shared__ float2 Wl[NC][NC];
  __shared__ float2 avec[NC];

  const int tid = threadIdx.x;
  const int f = blockIdx.x;
  const int b = blockIdx.y;
  const bool valid = tid < 500;
  const int n0 = tid*UK;                    // first frame owned
  const float norm = 1.0f/(float)NFRM;

  float igs[NC];
  #pragma unroll
  for (int c=0;c<NC;c++) {
    float g = fmaxf(gpart[b*NC+c]*INV_FN, EPS);
    igs[c] = __builtin_amdgcn_rsqf(g);
  }

  // load + rescale X (one float4 per plane per channel)
  float2 x[NC][UK];
  #pragma unroll
  for (int c=0;c<NC;c++) {
    #pragma unroll
    for (int k=0;k<UK;k++) x[c][k] = make_float2(0.f,0.f);
    if (valid) {
      const size_t rb = ((size_t)(b*NC+c)*NF + f)*NFRM;
      float4 r0 = *(const float4*)(Xsr + rb + n0);
      float4 i0 = *(const float4*)(Xsi + rb + n0);
      x[c][0] = make_float2(r0.x*igs[c], i0.x*igs[c]);
      x[c][1] = make_float2(r0.y*igs[c], i0.y*igs[c]);
      x[c][2] = make_float2(r0.z*igs[c], i0.z*igs[c]);
      x[c][3] = make_float2(r0.w*igs[c], i0.w*igs[c]);
    }
  }
  // precomputed weights (one float4 per channel)
  float w0g[NC][UK];
  #pragma unroll
  for (int c=0;c<NC;c++) {
    #pragma unroll
    for (int k=0;k<UK;k++) w0g[c][k] = 0.f;
    if (valid) {
      float4 w4 = *(const float4*)(w0gbuf + (b*NC+c)*NFRM + n0);
      w0g[c][0]=w4.x; w0g[c][1]=w4.y; w0g[c][2]=w4.z; w0g[c][3]=w4.w;
    }
  }
  // W load/init + rescale (wave 0 only; only wave 0 ever touches Wl)
  if (tid < 16) {
    const int c = tid>>2, d = tid&3;
    float2 w;
    if (FIRST) w = make_float2((c==d)?1.f:0.f, 0.f);
    else       w = Wg[(size_t)(b*NF+f)*16 + tid];
    Wl[c][d] = make_float2(w.x*igs[c], w.y*igs[c]);
  }

  // ---------- type-1 sweeps, fused in pairs (sources 0,1 then 2,3) ----------
  #pragma unroll
  for (int p=0;p<2;p++) {
    const int sg = 2*p, tu = 2*p+1;
    float acc[32];
    #pragma unroll
    for (int i=0;i<32;i++) acc[i] = 0.f;
    #pragma unroll
    for (int k=0;k<UK;k++) {
      float2 xs = x[sg][k], xt = x[tu][k];
      float m00 = xs.x*xs.x + xs.y*xs.y;
      float m11 = xt.x*xt.x + xt.y*xt.y;
      float prx = xs.x*xt.x + xs.y*xt.y;   // Re(Xsg conj(Xtu))
      float pry = xs.y*xt.x - xs.x*xt.y;   // Im(Xsg conj(Xtu))
      #pragma unroll
      for (int c=0;c<NC;c++) {
        float w = w0g[c][k]; float2 xc = x[c][k];
        acc[c]    += w*(xc.x*xs.x + xc.y*xs.y);  // A.re = Sum w Xc conj(Xsg)
        acc[4+c]  += w*(xc.y*xs.x - xc.x*xs.y);  // A.im
        acc[8+c]  += w*(xc.x*xt.x + xc.y*xt.y);  // B.re = Sum w Xc conj(Xtu)
        acc[12+c] += w*(xc.y*xt.x - xc.x*xt.y);  // B.im
        acc[16+c] += w*m00;                      // P = Sum w |Xsg|^2
        acc[20+c] += w*m11;                      // Q = Sum w |Xtu|^2
        acc[24+c] += w*prx;                      // S.re = Sum w Xsg conj(Xtu)
        acc[28+c] += w*pry;                      // S.im
      }
    }
    float vsum[32];
    REDUCE32();
    // sweep sg: v0 from A, P
    float2 v0[NC], v1[NC];
    #pragma unroll
    for (int c=0;c<NC;c++) {
      float dn = fmaxf(vsum[16+c]*norm, EPS);
      float rc = __builtin_amdgcn_rcpf(dn)*norm;
      v0[c] = make_float2(vsum[c]*rc, vsum[4+c]*rc);
    }
    v0[sg] = make_float2(1.0f - __builtin_amdgcn_rsqf(fmaxf(vsum[16+sg]*norm, EPS)), 0.f);
    // sweep tu: rank-1 corrected
    const float2 v0t = v0[tu];
    float d1t = 0.f;
    #pragma unroll
    for (int c=0;c<NC;c++) {
      float2 A = make_float2(vsum[c],    vsum[4+c]);
      float2 B = make_float2(vsum[8+c],  vsum[12+c]);
      float  Pp = vsum[16+c], Qq = vsum[20+c];
      float2 S = make_float2(vsum[24+c], vsum[28+c]);
      float2 ca = make_float2(v0t.x*A.x + v0t.y*A.y, v0t.x*A.y - v0t.y*A.x); // conj(v0t)*A
      float2 vc = v0[c];
      float2 vs = cmulf(vc, S);
      float2 vv = make_float2(vc.x*v0t.x + vc.y*v0t.y, vc.y*v0t.x - vc.x*v0t.y); // vc*conj(v0t)
      float2 n1 = make_float2(B.x - ca.x - vs.x + vv.x*Pp,
                              B.y - ca.y - vs.y + vv.y*Pp);
      float d1 = Qq - 2.f*(v0t.x*S.x - v0t.y*S.y) + (v0t.x*v0t.x + v0t.y*v0t.y)*Pp;
      if (c == tu) d1t = d1;
      float dn = fmaxf(d1*norm, EPS);
      float rc = __builtin_amdgcn_rcpf(dn)*norm;
      v1[c] = make_float2(n1.x*rc, n1.y*rc);
    }
    v1[tu] = make_float2(1.0f - __builtin_amdgcn_rsqf(fmaxf(d1t*norm, EPS)), 0.f);
    // apply both rank-1 updates to x (sequential, register-private)
    #pragma unroll
    for (int k=0;k<UK;k++) {
      float2 xs = x[sg][k];
      #pragma unroll
      for (int c=0;c<NC;c++) {
        float2 pr = cmulf(v0[c], xs);
        x[c][k].x -= pr.x; x[c][k].y -= pr.y;
      }
      float2 xt = x[tu][k];   // post-update0 value
      #pragma unroll
      for (int c=0;c<NC;c++) {
        float2 pr = cmulf(v1[c], xt);
        x[c][k].x -= pr.x; x[c][k].y -= pr.y;
      }
    }
    // apply both to W (wave 0, lockstep, program-ordered LDS ops)
    if (tid < 16) {
      const int c = tid>>2, d = tid&3;
      float2 ws0 = Wl[sg][d];
      float2 pr0 = cmulf(v0[c], ws0);
      float2 wv = Wl[c][d];
      wv.x -= pr0.x; wv.y -= pr0.y;
      Wl[c][d] = wv;
      float2 ws1 = Wl[tu][d];
      float2 pr1 = cmulf(v1[c], ws1);
      wv = Wl[c][d];
      wv.x -= pr1.x; wv.y -= pr1.y;
      Wl[c][d] = wv;
    }
  }

  // ---------- type-2 sweeps: both taps of each source fused in one reduce ----------
  #pragma unroll 1
  for (int s=0;s<NC;s++) {
    const size_t ob = ((size_t)(b*NC+s)*NF + f)*NFRM;
    // aligned 8-float window [n0-4, n0+4): tap t2 uses frames n0+k+t2-3 = win[k+1+t2]
    float winr[8], wini[8];
    {
      float4 m1r=make_float4(0,0,0,0), m1i=m1r, p0r=m1r, p0i=m1r;
      if (valid) {
        const float* tp = Xor_ + ob + n0;
        const float* ti = Xoi_ + ob + n0;
        if (tid > 0) { m1r = *(const float4*)(tp-4); m1i = *(const float4*)(ti-4); }
        p0r = *(const float4*)tp;  p0i = *(const float4*)ti;
      }
      winr[0]=m1r.x; winr[1]=m1r.y; winr[2]=m1r.z; winr[3]=m1r.w;
      winr[4]=p0r.x; winr[5]=p0r.y; winr[6]=p0r.z; winr[7]=p0r.w;
      wini[0]=m1i.x; wini[1]=m1i.y; wini[2]=m1i.z; wini[3]=m1i.w;
      wini[4]=p0i.x; wini[5]=p0i.y; wini[6]=p0i.z; wini[7]=p0i.w;
    }
    float acc[32];
    #pragma unroll
    for (int i=0;i<32;i++) acc[i] = 0.f;
    #pragma unroll
    for (int k=0;k<UK;k++) {
      float2 u0 = make_float2(winr[k+1], wini[k+1]);   // tap 0: frame n-3
      float2 u1 = make_float2(winr[k+2], wini[k+2]);   // tap 1: frame n-2
      float m0 = u0.x*u0.x + u0.y*u0.y;
      float m1 = u1.x*u1.x + u1.y*u1.y;
      float crx = u0.x*u1.x + u0.y*u1.y;   // Re(u0 conj(u1))
      float cry = u0.y*u1.x - u0.x*u1.y;   // Im(u0 conj(u1))
      #pragma unroll
      for (int c=0;c<NC;c++) {
        float w = w0g[c][k]; float2 xc = x[c][k];
        acc[c]    += w*(xc.x*u0.x + xc.y*u0.y);  // R0.re
        acc[4+c]  += w*(xc.y*u0.x - xc.x*u0.y);  // R0.im
        acc[8+c]  += w*(xc.x*u1.x + xc.y*u1.y);  // R1.re
        acc[12+c] += w*(xc.y*u1.x - xc.x*u1.y);  // R1.im
        acc[16+c] += w*m0;                       // den0
        acc[20+c] += w*m1;                       // den1
        acc[24+c] += w*crx;                      // C.re
        acc[28+c] += w*cry;                      // C.im
      }
    }
    float vsum[32];
    REDUCE32();
    float2 v0[NC], v1[NC];
    #pragma unroll
    for (int c=0;c<NC;c++) {
      float dn0 = fmaxf(vsum[16+c]*norm, EPS);
      float rc0 = __builtin_amdgcn_rcpf(dn0)*norm;
      v0[c] = make_float2(vsum[c]*rc0, vsum[4+c]*rc0);
      // num1 = R1 - v0*C  (tap signals fixed -> den1 unchanged)
      float2 C = make_float2(vsum[24+c], vsum[28+c]);
      float2 n1 = make_float2(vsum[8+c]  - (v0[c].x*C.x - v0[c].y*C.y),
                              vsum[12+c] - (v0[c].x*C.y + v0[c].y*C.x));
      float dn1 = fmaxf(vsum[20+c]*norm, EPS);
      float rc1 = __builtin_amdgcn_rcpf(dn1)*norm;
      v1[c] = make_float2(n1.x*rc1, n1.y*rc1);
    }
    #pragma unroll
    for (int k=0;k<UK;k++) {
      float2 u0 = make_float2(winr[k+1], wini[k+1]);
      float2 u1 = make_float2(winr[k+2], wini[k+2]);
      #pragma unroll
      for (int c=0;c<NC;c++) {
        float2 p0 = cmulf(v0[c], u0);
        float2 p1 = cmulf(v1[c], u1);
        x[c][k].x -= p0.x + p1.x;
        x[c][k].y -= p0.y + p1.y;
      }
    }
  }

  // ---------- epilogue ----------
  if (LAST) {
    if (tid == 0) {
      float2 A[4][4], bb[4], xv[4];
      for (int i=0;i<4;i++)
        for (int j=0;j<4;j++)
          A[i][j] = Wl[j][i];
      for (int i=0;i<4;i++) A[i][i].x += 1e-6f;
      bb[0] = make_float2(1.f,0.f);
      bb[1] = make_float2(0.f,0.f);
      bb[2] = make_float2(0.f,0.f);
      bb[3] = make_float2(0.f,0.f);
      for (int col=0; col<4; ++col) {
        int p = col;
        float best = A[col][col].x*A[col][col].x + A[col][col].y*A[col][col].y;
        for (int r=col+1;r<4;r++) {
          float m = A[r][col].x*A[r][col].x + A[r][col].y*A[r][col].y;
          if (m > best) { best = m; p = r; }
        }
        if (p != col) {
          for (int j=0;j<4;j++) { float2 ts = A[col][j]; A[col][j] = A[p][j]; A[p][j] = ts; }
          float2 ts = bb[col]; bb[col] = bb[p]; bb[p] = ts;
        }
        float2 piv = A[col][col];
        float ib = 1.0f / (piv.x*piv.x + piv.y*piv.y);
        float2 inv = make_float2(piv.x*ib, -piv.y*ib);
        for (int r=col+1;r<4;r++) {
          float2 fac = cmulf(A[r][col], inv);
          for (int j=col;j<4;j++) {
            float2 pr = cmulf(fac, A[col][j]);
            A[r][j].x -= pr.x; A[r][j].y -= pr.y;
          }
          float2 pb = cmulf(fac, bb[col]);
          bb[r].x -= pb.x; bb[r].y -= pb.y;
        }
      }
      for (int r=3;r>=0;r--) {
        float2 t = bb[r];
        for (int j=r+1;j<4;j++) {
          float2 pr = cmulf(A[r][j], xv[j]);
          t.x -= pr.x; t.y -= pr.y;
        }
        float2 d = A[r][r];
        float ib = 1.0f/(d.x*d.x + d.y*d.y);
        xv[r] = cmulf(t, make_float2(d.x*ib, -d.y*ib));
      }
      for (int c=0;c<4;c++) avec[c] = xv[c];
    }
    __syncthreads();
    if (valid) {
      #pragma unroll
      for (int c=0;c<NC;c++) {
        const size_t rb = ((size_t)(b*NC+c)*NF + f)*NFRM;
        float2 a = avec[c];
        float2 y0 = cmulf(a, x[c][0]), y1 = cmulf(a, x[c][1]);
        float2 y2 = cmulf(a, x[c][2]), y3 = cmulf(a, x[c][3]);
        *(float4*)(Xdr + rb + n0) = make_float4(y0.x,y1.x,y2.x,y3.x);
        *(float4*)(Xdi + rb + n0) = make_float4(y0.y,y1.y,y2.y,y3.y);
      }
    }
  } else {
    if (valid) {
      #pragma unroll
      for (int c=0;c<NC;c++) {
        const size_t rb = ((size_t)(b*NC+c)*NF + f)*NFRM;
        *(float4*)(Xdr + rb + n0) = make_float4(x[c][0].x,x[c][1].x,x[c][2].x,x[c][3].x);
        *(float4*)(Xdi + rb + n0) = make_float4(x[c][0].y,x[c][1].y,x[c][2].y,x[c][3].y);
      }
    }
    if (tid < 16) Wg[(size_t)(b*NF+f)*16 + tid] = Wl[tid>>2][tid&3];
  }
}

extern "C" void kernel_launch(void* const* d_in, const int* in_sizes, int n_in,
                              void* d_out, int out_size, void* d_ws, size_t ws_size,
                              hipStream_t stream)
{
  (void)in_sizes; (void)n_in; (void)out_size; (void)ws_size;
  const float* xr_in = (const float*)d_in[0];
  const float* xi_in = (const float*)d_in[1];
  float* outr = (float*)d_out;
  float* outi = outr + PLANE;

  char*  ws    = (char*)d_ws;
  float* rsum  = (float*)ws;                       // 32000 floats = 128 KB
  float* w0g   = (float*)(ws + 128000);            // 32000 floats = 128 KB
  float* gpart = (float*)(ws + 256000);            // 48 floats
  float2* Wg   = (float2*)(ws + 256000 + 256);     // 1028*16 float2 = 131,584 B

  dim3 grR(2, RFC, NB*NC);    // 928 blocks
  dim3 grU(NF, NB);           // 1028 blocks

  k_zero<<<126, 256, 0, stream>>>(rsum, gpart);

  // iteration 0 (X = original input)
  k_r<<<grR, 256, 0, stream>>>(xr_in, xi_in, rsum, gpart + 0);
  k_w<<<125, 256, 0, stream>>>(rsum, gpart + 0, w0g);
  k_u<true,false><<<grU, UT, 0, stream>>>(xr_in, xi_in, xr_in, xi_in,
                                          outr, outi, w0g, gpart + 0, Wg);
  // iteration 1
  k_r<<<grR, 256, 0, stream>>>(outr, outi, rsum, gpart + 16);
  k_w<<<125, 256, 0, stream>>>(rsum, gpart + 16, w0g);
  k_u<false,false><<<grU, UT, 0, stream>>>(outr, outi, xr_in, xi_in,
                                           outr, outi, w0g, gpart + 16, Wg);
  // iteration 2 + projection_back
  k_r<<<grR, 256, 0, stream>>>(outr, outi, rsum, gpart + 32);
  k_w<<<125, 256, 0, stream>>>(rsum, gpart + 32, w0g);
  k_u<false,true><<<grU, UT, 0, stream>>>(outr, outi, xr_in, xi_in,
                                          outr, outi, w0g, gpart + 32, Wg);
}